// Round 5
// baseline (570.667 us; speedup 1.0000x reference)
//
#include <hip/hip_runtime.h>
#include <math.h>

// ---------------------------------------------------------------------------
// GNN TLearner forward, MI355X.  (R4: +csrc fill to break agg2's dependent
// gather chain; float2 edge-attr loads; 3-tier ws fallback. Core held.)
//
// Algebraic restructuring vs reference (re-audited R3):
//  * peer MLP folded to node level:
//      h_peer[v] = relu(deg_inv[v]*(deg[v]*(x[v]@W_px + b_peer) + ea_sum[v]@W_pe))
//    (exact: peer_feat gathers x at dst == scatter destination; segment_sum linear)
//  * h_edge_2hop[v] = deg_inv[v] * seg(eagg[src], dst)[v]  (deg_inv[dst] const/segment)
//  * relu(f_emb) dropped (all components >= 0)
//  * deg[v] == in-degree == rowstart[v+1]-rowstart[v] (exact)
//
// Pipeline (tier A):
//   memset(counts) -> k_count -> k_scan (1 block) -> k_fill (edgeid + csrc)
//   -> k_agg1 (eagg,easum; no atomics) -> k_agg2c (h2 via csrc; no atomics)
//   -> k_nodeA (f_emb) -> k_nodeB (emb + heads)
// Tier B: no csrc (agg2 double-gathers via edgeid+src).  Tier C: atomic path.
//
// Tier A ws (4B elems): counts[N] | rowstart[N+4] | cursor[N] | edgeid[E] |
//                       csrc[E] | eagg[16N] | easum[2N] | h2[16N] | femb[112N]
// out layout (floats): y0[N] | y1[N] | emb[64N]
// ---------------------------------------------------------------------------

// ============================ CSR-path kernels =============================

__global__ void k_count(const int* __restrict__ dst, int* __restrict__ counts,
                        int nE) {
    int e = blockIdx.x * blockDim.x + threadIdx.x;
    if (e < nE) atomicAdd(&counts[dst[e]], 1);
}

// single-workgroup exclusive scan of counts[0..nN) -> rowstart & cursor
__global__ __launch_bounds__(1024) void k_scan(const int* __restrict__ counts,
                                               int* __restrict__ rowstart,
                                               int* __restrict__ cursor,
                                               int nN, int nE) {
    __shared__ int s[1024];
    int t = threadIdx.x;
    int C = (nN + 1023) / 1024;
    int lo = t * C, hi = min(lo + C, nN);
    int sum = 0;
    for (int i = lo; i < hi; ++i) sum += counts[i];
    s[t] = sum;
    __syncthreads();
    for (int off = 1; off < 1024; off <<= 1) {
        int v = (t >= off) ? s[t - off] : 0;
        __syncthreads();
        s[t] += v;
        __syncthreads();
    }
    int run = (t == 0) ? 0 : s[t - 1];
    for (int i = lo; i < hi; ++i) {
        rowstart[i] = run;
        cursor[i] = run;
        run += counts[i];
    }
    if (t == 0) rowstart[nN] = nE;
}

// WRITE_CSRC: also materialize src reordered into CSR slot order, so the
// consumer avoids the dependent gather src[edgeid[s]].
template <bool WRITE_CSRC>
__global__ void k_fill(const int* __restrict__ dst, const int* __restrict__ src,
                       int* __restrict__ cursor, int* __restrict__ edgeid,
                       int* __restrict__ csrc, int nE) {
    int e = blockIdx.x * blockDim.x + threadIdx.x;
    if (e < nE) {
        int slot = atomicAdd(&cursor[dst[e]], 1);
        edgeid[slot] = e;
        if (WRITE_CSRC) csrc[slot] = src[e];   // src[e] coalesced read
    }
}

// 16 threads per node; lane j owns channel j. Edge loads are group-broadcast.
__global__ void k_agg1(const float* __restrict__ ea, const int* __restrict__ edgeid,
                       const int* __restrict__ rowstart,
                       const float* __restrict__ We, const float* __restrict__ be,
                       float* __restrict__ eagg, float* __restrict__ easum, int nN) {
    __shared__ float w[48];   // [0..15]=We row0, [16..31]=We row1, [32..47]=be
    if (threadIdx.x < 32) w[threadIdx.x] = We[threadIdx.x];
    else if (threadIdx.x < 48) w[threadIdx.x] = be[threadIdx.x - 32];
    __syncthreads();
    const float2* ea2 = (const float2*)ea;
    int gid = blockIdx.x * blockDim.x + threadIdx.x;
    int v = gid >> 4, j = gid & 15;
    if (v >= nN) return;
    int s0 = rowstart[v], s1 = rowstart[v + 1];
    float acc = 0.f, aE = 0.f;
    for (int s = s0; s < s1; ++s) {
        int e = edgeid[s];
        float2 eav = ea2[e];                   // single 8B gather
        acc += fmaxf(fmaf(eav.x, w[j], fmaf(eav.y, w[16 + j], w[32 + j])), 0.f);
        if (j == 0) aE += eav.x;
        else if (j == 1) aE += eav.y;
    }
    eagg[v * 16 + j] = acc;
    if (j == 0) easum[2 * v] = aE;
    else if (j == 1) easum[2 * v + 1] = aE;
}

// Tier A: 16 threads per node; csrc[s] sequential -> one random eagg gather.
__global__ void k_agg2c(const int* __restrict__ csrc,
                        const int* __restrict__ rowstart,
                        const float* __restrict__ eagg, float* __restrict__ h2,
                        int nN) {
    int gid = blockIdx.x * blockDim.x + threadIdx.x;
    int v = gid >> 4, j = gid & 15;
    if (v >= nN) return;
    int s0 = rowstart[v], s1 = rowstart[v + 1];
    float acc = 0.f;
    for (int s = s0; s < s1; ++s) {
        int sn = csrc[s];                      // coalesced within group
        acc += eagg[sn * 16 + j];              // 64B line per 16-lane group
    }
    h2[v * 16 + j] = acc;
}

// Tier B: double-gather variant (edgeid -> src).
__global__ void k_agg2(const int* __restrict__ src, const int* __restrict__ edgeid,
                       const int* __restrict__ rowstart,
                       const float* __restrict__ eagg, float* __restrict__ h2,
                       int nN) {
    int gid = blockIdx.x * blockDim.x + threadIdx.x;
    int v = gid >> 4, j = gid & 15;
    if (v >= nN) return;
    int s0 = rowstart[v], s1 = rowstart[v + 1];
    float acc = 0.f;
    for (int s = s0; s < s1; ++s) {
        int sn = src[edgeid[s]];
        acc += eagg[sn * 16 + j];
    }
    h2[v * 16 + j] = acc;
}

// ========================= atomic-path (fallback) ==========================

__global__ void k_edge1(const float* __restrict__ ea, const int* __restrict__ dst,
                        const float* __restrict__ We, const float* __restrict__ be,
                        float* __restrict__ deg, float* __restrict__ easum,
                        float* __restrict__ eagg, int nE) {
    __shared__ float w[48];
    if (threadIdx.x < 32) w[threadIdx.x] = We[threadIdx.x];
    else if (threadIdx.x < 48) w[threadIdx.x] = be[threadIdx.x - 32];
    __syncthreads();
    const float2* ea2 = (const float2*)ea;
    long long stride = (long long)gridDim.x * blockDim.x;
    for (long long gid = (long long)blockIdx.x * blockDim.x + threadIdx.x;
         gid < 16LL * nE; gid += stride) {
        int e = (int)(gid >> 4);
        int j = (int)(gid & 15);
        int d = dst[e];
        float2 eav = ea2[e];
        float h = fmaxf(fmaf(eav.x, w[j], fmaf(eav.y, w[16 + j], w[32 + j])), 0.f);
        atomicAdd(&eagg[d * 16 + j], h);
        if (j == 0)      atomicAdd(&deg[d], 1.0f);
        else if (j == 1) atomicAdd(&easum[2 * d], eav.x);
        else if (j == 2) atomicAdd(&easum[2 * d + 1], eav.y);
    }
}

__global__ void k_edge2(const int* __restrict__ src, const int* __restrict__ dst,
                        const float* __restrict__ eagg, float* __restrict__ h2,
                        int nE) {
    long long stride = (long long)gridDim.x * blockDim.x;
    for (long long gid = (long long)blockIdx.x * blockDim.x + threadIdx.x;
         gid < 16LL * nE; gid += stride) {
        int e = (int)(gid >> 4);
        int j = (int)(gid & 15);
        atomicAdd(&h2[dst[e] * 16 + j], eagg[src[e] * 16 + j]);
    }
}

// ============================= node kernels ================================
// DEG_FROM_CSR: deg = rowstart[v+1]-rowstart[v]; else read float deg[].
template <bool DEG_FROM_CSR>
__global__ __launch_bounds__(256) void k_nodeA(
    const float* __restrict__ x,
    const float* __restrict__ W_ego, const float* __restrict__ b_ego,
    const float* __restrict__ W_peer, const float* __restrict__ b_peer,
    const float* __restrict__ degf, const int* __restrict__ rowstart,
    const float* __restrict__ easum,
    const float* __restrict__ eagg, const float* __restrict__ h2,
    float* __restrict__ femb, int nN) {
    __shared__ float sWe[64 * 32];   // W_ego [k][32]
    __shared__ float sWp[64 * 48];   // W_peer rows 0..63 (x part)
    __shared__ float sWpe[96];       // W_peer rows 64,65 (edge-attr part)
    __shared__ float sbe[32];
    __shared__ float sbp[48];
    for (int i = threadIdx.x; i < 64 * 32; i += 256) sWe[i] = W_ego[i];
    for (int i = threadIdx.x; i < 64 * 48; i += 256) sWp[i] = W_peer[i];
    if (threadIdx.x < 96) sWpe[threadIdx.x] = W_peer[64 * 48 + threadIdx.x];
    if (threadIdx.x < 32) sbe[threadIdx.x] = b_ego[threadIdx.x];
    if (threadIdx.x < 48) sbp[threadIdx.x] = b_peer[threadIdx.x];
    __syncthreads();

    int v = blockIdx.x * 256 + threadIdx.x;
    if (v >= nN) return;

    float accE[32];
    float accP[48];
#pragma unroll
    for (int j = 0; j < 32; ++j) accE[j] = 0.f;
#pragma unroll
    for (int j = 0; j < 48; ++j) accP[j] = 0.f;

    const float4* x4 = (const float4*)(x + (long long)v * 64);
#pragma unroll 4
    for (int k4 = 0; k4 < 16; ++k4) {
        float4 xv = x4[k4];
        float xs[4] = {xv.x, xv.y, xv.z, xv.w};
#pragma unroll
        for (int t = 0; t < 4; ++t) {
            int k = 4 * k4 + t;
            float xk = xs[t];
            const float* we = &sWe[k * 32];
#pragma unroll
            for (int j = 0; j < 32; ++j) accE[j] = fmaf(xk, we[j], accE[j]);
            const float* wp = &sWp[k * 48];
#pragma unroll
            for (int j = 0; j < 48; ++j) accP[j] = fmaf(xk, wp[j], accP[j]);
        }
    }

    float dg;
    if (DEG_FROM_CSR) dg = (float)(rowstart[v + 1] - rowstart[v]);
    else              dg = degf[v];
    float dinv = dg > 0.f ? 1.0f / sqrtf(dg) : 0.f;
    float ea0 = easum[2 * v], ea1 = easum[2 * v + 1];

    float* fo = femb + (long long)v * 112;
#pragma unroll
    for (int j = 0; j < 32; ++j) fo[j] = fmaxf(accE[j] + sbe[j], 0.f);
#pragma unroll
    for (int j = 0; j < 16; ++j) fo[32 + j] = eagg[v * 16 + j];
#pragma unroll
    for (int j = 0; j < 16; ++j) fo[48 + j] = dinv * h2[v * 16 + j];
#pragma unroll
    for (int j = 0; j < 48; ++j) {
        float t = dg * (accP[j] + sbp[j]) + fmaf(ea0, sWpe[j], ea1 * sWpe[48 + j]);
        fo[64 + j] = fmaxf(dinv * t, 0.f);
    }
}

__global__ __launch_bounds__(256) void k_nodeB(
    const float* __restrict__ femb,
    const float* __restrict__ W_emb, const float* __restrict__ b_emb,
    const float* __restrict__ bn_g, const float* __restrict__ bn_b,
    const float* __restrict__ bn_m, const float* __restrict__ bn_v,
    const float* __restrict__ W0, const float* __restrict__ b0,
    const float* __restrict__ W1, const float* __restrict__ b1,
    float* __restrict__ out, int nN) {
    __shared__ float sW[112 * 64];   // W_emb [k][64]
    __shared__ float sbias[64], sScale[64], sShift[64], sW0[64], sW1[64];
    for (int i = threadIdx.x; i < 112 * 64; i += 256) sW[i] = W_emb[i];
    if (threadIdx.x < 64) {
        int j = threadIdx.x;
        sbias[j] = b_emb[j];
        float rstd = 1.0f / sqrtf(bn_v[j] + 1e-5f);
        float sc = bn_g[j] * rstd;
        sScale[j] = sc;
        sShift[j] = bn_b[j] - bn_m[j] * sc;
        sW0[j] = W0[j];
        sW1[j] = W1[j];
    }
    __syncthreads();

    int v = blockIdx.x * 256 + threadIdx.x;
    if (v >= nN) return;

    float acc[64];
#pragma unroll
    for (int j = 0; j < 64; ++j) acc[j] = 0.f;

    const float4* f4 = (const float4*)(femb + (long long)v * 112);
#pragma unroll 4
    for (int k4 = 0; k4 < 28; ++k4) {
        float4 fv = f4[k4];
        float fs[4] = {fv.x, fv.y, fv.z, fv.w};
#pragma unroll
        for (int t = 0; t < 4; ++t) {
            int k = 4 * k4 + t;
            float fk = fs[t];
            const float* wr = &sW[k * 64];
#pragma unroll
            for (int j = 0; j < 64; ++j) acc[j] = fmaf(fk, wr[j], acc[j]);
        }
    }

    float y0 = 0.f, y1 = 0.f;
#pragma unroll
    for (int j = 0; j < 64; ++j) {
        float e = fmaxf(acc[j] + sbias[j], 0.f);
        e = fmaf(e, sScale[j], sShift[j]);   // BN inference affine
        e = tanhf(e);
        acc[j] = e;
        y0 = fmaf(e, sW0[j], y0);
        y1 = fmaf(e, sW1[j], y1);
    }

    float4* o4 = (float4*)(out + 2LL * nN + (long long)v * 64);
#pragma unroll
    for (int j4 = 0; j4 < 16; ++j4)
        o4[j4] = make_float4(acc[4 * j4], acc[4 * j4 + 1], acc[4 * j4 + 2], acc[4 * j4 + 3]);
    out[v] = y0 + b0[0];
    out[nN + v] = y1 + b1[0];
}

// ================================ launch ===================================

extern "C" void kernel_launch(void* const* d_in, const int* in_sizes, int n_in,
                              void* d_out, int out_size, void* d_ws, size_t ws_size,
                              hipStream_t stream) {
    const float* x      = (const float*)d_in[0];
    const float* ea     = (const float*)d_in[1];
    const int*   src    = (const int*)d_in[3];
    const int*   dst    = (const int*)d_in[4];
    const float* W_peer = (const float*)d_in[5];
    const float* b_peer = (const float*)d_in[6];
    const float* W_ego  = (const float*)d_in[7];
    const float* b_ego  = (const float*)d_in[8];
    const float* W_edge = (const float*)d_in[9];
    const float* b_edge = (const float*)d_in[10];
    const float* W_emb  = (const float*)d_in[11];
    const float* b_emb  = (const float*)d_in[12];
    const float* bn_g   = (const float*)d_in[13];
    const float* bn_b   = (const float*)d_in[14];
    const float* bn_m   = (const float*)d_in[15];
    const float* bn_v   = (const float*)d_in[16];
    const float* W0     = (const float*)d_in[17];
    const float* b0     = (const float*)d_in[18];
    const float* W1     = (const float*)d_in[19];
    const float* b1     = (const float*)d_in[20];

    int nE = in_sizes[3];
    int nN = in_sizes[2];

    int nBlocks  = (nN + 255) / 256;          // node kernels
    int ngBlocks = (16 * nN + 255) / 256;     // 16-thread-per-node kernels
    int eBlocks1 = (nE + 255) / 256;          // 1-thread-per-edge kernels

    // ws demand (4B elems): tierA = 3N+4 + 2E + 146N; tierB = 3N+4 + E + 146N
    size_t tierA = 4ULL * ((size_t)149 * nN + 4 + 2ULL * (size_t)nE);
    size_t tierB = 4ULL * ((size_t)149 * nN + 4 + (size_t)nE);

    if (ws_size >= tierB) {
        bool haveCsrc = (ws_size >= tierA);
        int*   wsi      = (int*)d_ws;
        int*   counts   = wsi;                       // N
        int*   rowstart = wsi + nN;                  // N+1 (padded to N+4)
        int*   cursor   = wsi + 2 * nN + 4;          // N
        int*   edgeid   = wsi + 3 * nN + 4;          // E
        int*   csrc     = edgeid + nE;               // E (tier A only)
        int*   tail     = haveCsrc ? (csrc + nE) : (edgeid + nE);
        float* eagg     = (float*)tail;              // 16N (16B aligned: offsets even)
        float* easum    = eagg + 16LL * nN;          // 2N
        float* h2       = easum + 2LL * nN;          // 16N
        float* femb     = h2 + 16LL * nN;            // 112N

        hipMemsetAsync(counts, 0, sizeof(int) * (size_t)nN, stream);
        k_count<<<eBlocks1, 256, 0, stream>>>(dst, counts, nE);
        k_scan<<<1, 1024, 0, stream>>>(counts, rowstart, cursor, nN, nE);
        if (haveCsrc) {
            k_fill<true><<<eBlocks1, 256, 0, stream>>>(dst, src, cursor, edgeid,
                                                       csrc, nE);
        } else {
            k_fill<false><<<eBlocks1, 256, 0, stream>>>(dst, src, cursor, edgeid,
                                                        nullptr, nE);
        }
        k_agg1<<<ngBlocks, 256, 0, stream>>>(ea, edgeid, rowstart, W_edge, b_edge,
                                             eagg, easum, nN);
        if (haveCsrc) {
            k_agg2c<<<ngBlocks, 256, 0, stream>>>(csrc, rowstart, eagg, h2, nN);
        } else {
            k_agg2<<<ngBlocks, 256, 0, stream>>>(src, edgeid, rowstart, eagg, h2, nN);
        }
        k_nodeA<true><<<nBlocks, 256, 0, stream>>>(x, W_ego, b_ego, W_peer, b_peer,
                                                   nullptr, rowstart, easum,
                                                   eagg, h2, femb, nN);
        k_nodeB<<<nBlocks, 256, 0, stream>>>(femb, W_emb, b_emb, bn_g, bn_b, bn_m,
                                             bn_v, W0, b0, W1, b1, (float*)d_out, nN);
    } else {
        // ---------------- atomic fallback ----------------
        float* wsf   = (float*)d_ws;
        float* deg   = wsf;                  // N
        float* easum = wsf + nN;             // 2N
        float* eagg  = wsf + 3LL * nN;       // 16N
        float* h2    = wsf + 19LL * nN;      // 16N
        float* femb  = wsf + 35LL * nN;      // 112N

        hipMemsetAsync(wsf, 0, sizeof(float) * 35ULL * nN, stream);
        const int eBlocks = 2048;
        k_edge1<<<eBlocks, 256, 0, stream>>>(ea, dst, W_edge, b_edge, deg, easum,
                                             eagg, nE);
        k_edge2<<<eBlocks, 256, 0, stream>>>(src, dst, eagg, h2, nE);
        k_nodeA<false><<<nBlocks, 256, 0, stream>>>(x, W_ego, b_ego, W_peer, b_peer,
                                                    deg, nullptr, easum,
                                                    eagg, h2, femb, nN);
        k_nodeB<<<nBlocks, 256, 0, stream>>>(femb, W_emb, b_emb, bn_g, bn_b, bn_m,
                                             bn_v, W0, b0, W1, b1, (float*)d_out, nN);
    }
}

// Round 6
// 538.208 us; speedup vs baseline: 1.0603x; 1.0603x over previous
//
#include <hip/hip_runtime.h>
#include <math.h>

// ---------------------------------------------------------------------------
// GNN TLearner forward, MI355X.
// R5: CSR fill writes ONE packed int4 payload {ea0,ea1,src,0} per edge
//     (was: two scattered 4B stores -> 145MB WRITE_SIZE measured in R4).
//     k_agg1 edge data now read sequentially; edgeid array eliminated.
//
// Algebraic restructuring vs reference (audited R3):
//  * peer MLP folded to node level:
//      h_peer[v] = relu(deg_inv[v]*(deg[v]*(x[v]@W_px + b_peer) + ea_sum[v]@W_pe))
//  * h_edge_2hop[v] = deg_inv[v] * seg(eagg[src], dst)[v]
//  * relu(f_emb) dropped (all components >= 0)
//  * deg[v] == rowstart[v+1]-rowstart[v] (exact)
//
// Pipeline (packed tier):
//   memset(counts) -> k_count -> k_scan -> k_fillP (payload)
//   -> k_aggP1 (eagg,easum; sequential payload) -> k_aggP2 (h2; seq + 64B gather)
//   -> k_nodeA -> k_nodeB
// Fallbacks: old csrc tier, then atomic tier (ws_size-keyed).
//
// Packed ws (4B elems): counts[N] | rowstart[N+4] | cursor[N] | payload[4E]
//                       | eagg[16N] | easum[2N] | h2[16N] | femb[112N]
// out layout (floats): y0[N] | y1[N] | emb[64N]
// ---------------------------------------------------------------------------

// ============================ CSR-build kernels ============================

__global__ void k_count(const int* __restrict__ dst, int* __restrict__ counts,
                        int nE) {
    int e = blockIdx.x * blockDim.x + threadIdx.x;
    if (e < nE) atomicAdd(&counts[dst[e]], 1);
}

// single-workgroup exclusive scan of counts[0..nN) -> rowstart & cursor
__global__ __launch_bounds__(1024) void k_scan(const int* __restrict__ counts,
                                               int* __restrict__ rowstart,
                                               int* __restrict__ cursor,
                                               int nN, int nE) {
    __shared__ int s[1024];
    int t = threadIdx.x;
    int C = (nN + 1023) / 1024;
    int lo = t * C, hi = min(lo + C, nN);
    int sum = 0;
    for (int i = lo; i < hi; ++i) sum += counts[i];
    s[t] = sum;
    __syncthreads();
    for (int off = 1; off < 1024; off <<= 1) {
        int v = (t >= off) ? s[t - off] : 0;
        __syncthreads();
        s[t] += v;
        __syncthreads();
    }
    int run = (t == 0) ? 0 : s[t - 1];
    for (int i = lo; i < hi; ++i) {
        rowstart[i] = run;
        cursor[i] = run;
        run += counts[i];
    }
    if (t == 0) rowstart[nN] = nE;
}

// ============================ packed tier ==================================

// one scattered 16B store per edge (single dirty line), vs 2x4B in R4
__global__ void k_fillP(const int* __restrict__ dst, const int* __restrict__ src,
                        const float* __restrict__ ea, int* __restrict__ cursor,
                        int4* __restrict__ payload, int nE) {
    int e = blockIdx.x * blockDim.x + threadIdx.x;
    if (e < nE) {
        float2 eav = ((const float2*)ea)[e];   // coalesced 8B
        int sn = src[e];                       // coalesced 4B
        int slot = atomicAdd(&cursor[dst[e]], 1);
        int4 p;
        p.x = __float_as_int(eav.x);
        p.y = __float_as_int(eav.y);
        p.z = sn;
        p.w = 0;
        payload[slot] = p;                     // one 16B store
    }
}

// 16 threads/node; payload read sequentially (16B broadcast per group-step)
__global__ void k_aggP1(const int4* __restrict__ payload,
                        const int* __restrict__ rowstart,
                        const float* __restrict__ We, const float* __restrict__ be,
                        float* __restrict__ eagg, float* __restrict__ easum,
                        int nN) {
    __shared__ float w[48];   // [0..15]=We row0, [16..31]=We row1, [32..47]=be
    if (threadIdx.x < 32) w[threadIdx.x] = We[threadIdx.x];
    else if (threadIdx.x < 48) w[threadIdx.x] = be[threadIdx.x - 32];
    __syncthreads();
    int gid = blockIdx.x * blockDim.x + threadIdx.x;
    int v = gid >> 4, j = gid & 15;
    if (v >= nN) return;
    int s0 = rowstart[v], s1 = rowstart[v + 1];
    float acc = 0.f, aE = 0.f;
    for (int s = s0; s < s1; ++s) {
        int4 p = payload[s];
        float ea0 = __int_as_float(p.x), ea1 = __int_as_float(p.y);
        acc += fmaxf(fmaf(ea0, w[j], fmaf(ea1, w[16 + j], w[32 + j])), 0.f);
        if (j == 0) aE += ea0;
        else if (j == 1) aE += ea1;
    }
    eagg[v * 16 + j] = acc;
    if (j == 0) easum[2 * v] = aE;
    else if (j == 1) easum[2 * v + 1] = aE;
}

// 16 threads/node; sequential src + one coalesced 64B eagg line per edge
__global__ void k_aggP2(const int4* __restrict__ payload,
                        const int* __restrict__ rowstart,
                        const float* __restrict__ eagg, float* __restrict__ h2,
                        int nN) {
    int gid = blockIdx.x * blockDim.x + threadIdx.x;
    int v = gid >> 4, j = gid & 15;
    if (v >= nN) return;
    int s0 = rowstart[v], s1 = rowstart[v + 1];
    float acc = 0.f;
    for (int s = s0; s < s1; ++s) {
        int sn = payload[s].z;                 // sequential (stride 16B)
        acc += eagg[sn * 16 + j];              // 64B line per 16-lane group
    }
    h2[v * 16 + j] = acc;
}

// ========================= old csrc tier (fallback) ========================

template <bool WRITE_CSRC>
__global__ void k_fill(const int* __restrict__ dst, const int* __restrict__ src,
                       int* __restrict__ cursor, int* __restrict__ edgeid,
                       int* __restrict__ csrc, int nE) {
    int e = blockIdx.x * blockDim.x + threadIdx.x;
    if (e < nE) {
        int slot = atomicAdd(&cursor[dst[e]], 1);
        edgeid[slot] = e;
        if (WRITE_CSRC) csrc[slot] = src[e];
    }
}

__global__ void k_agg1(const float* __restrict__ ea, const int* __restrict__ edgeid,
                       const int* __restrict__ rowstart,
                       const float* __restrict__ We, const float* __restrict__ be,
                       float* __restrict__ eagg, float* __restrict__ easum, int nN) {
    __shared__ float w[48];
    if (threadIdx.x < 32) w[threadIdx.x] = We[threadIdx.x];
    else if (threadIdx.x < 48) w[threadIdx.x] = be[threadIdx.x - 32];
    __syncthreads();
    const float2* ea2 = (const float2*)ea;
    int gid = blockIdx.x * blockDim.x + threadIdx.x;
    int v = gid >> 4, j = gid & 15;
    if (v >= nN) return;
    int s0 = rowstart[v], s1 = rowstart[v + 1];
    float acc = 0.f, aE = 0.f;
    for (int s = s0; s < s1; ++s) {
        int e = edgeid[s];
        float2 eav = ea2[e];
        acc += fmaxf(fmaf(eav.x, w[j], fmaf(eav.y, w[16 + j], w[32 + j])), 0.f);
        if (j == 0) aE += eav.x;
        else if (j == 1) aE += eav.y;
    }
    eagg[v * 16 + j] = acc;
    if (j == 0) easum[2 * v] = aE;
    else if (j == 1) easum[2 * v + 1] = aE;
}

__global__ void k_agg2c(const int* __restrict__ csrc,
                        const int* __restrict__ rowstart,
                        const float* __restrict__ eagg, float* __restrict__ h2,
                        int nN) {
    int gid = blockIdx.x * blockDim.x + threadIdx.x;
    int v = gid >> 4, j = gid & 15;
    if (v >= nN) return;
    int s0 = rowstart[v], s1 = rowstart[v + 1];
    float acc = 0.f;
    for (int s = s0; s < s1; ++s) {
        int sn = csrc[s];
        acc += eagg[sn * 16 + j];
    }
    h2[v * 16 + j] = acc;
}

// ========================= atomic tier (fallback) ==========================

__global__ void k_edge1(const float* __restrict__ ea, const int* __restrict__ dst,
                        const float* __restrict__ We, const float* __restrict__ be,
                        float* __restrict__ deg, float* __restrict__ easum,
                        float* __restrict__ eagg, int nE) {
    __shared__ float w[48];
    if (threadIdx.x < 32) w[threadIdx.x] = We[threadIdx.x];
    else if (threadIdx.x < 48) w[threadIdx.x] = be[threadIdx.x - 32];
    __syncthreads();
    const float2* ea2 = (const float2*)ea;
    long long stride = (long long)gridDim.x * blockDim.x;
    for (long long gid = (long long)blockIdx.x * blockDim.x + threadIdx.x;
         gid < 16LL * nE; gid += stride) {
        int e = (int)(gid >> 4);
        int j = (int)(gid & 15);
        int d = dst[e];
        float2 eav = ea2[e];
        float h = fmaxf(fmaf(eav.x, w[j], fmaf(eav.y, w[16 + j], w[32 + j])), 0.f);
        atomicAdd(&eagg[d * 16 + j], h);
        if (j == 0)      atomicAdd(&deg[d], 1.0f);
        else if (j == 1) atomicAdd(&easum[2 * d], eav.x);
        else if (j == 2) atomicAdd(&easum[2 * d + 1], eav.y);
    }
}

__global__ void k_edge2(const int* __restrict__ src, const int* __restrict__ dst,
                        const float* __restrict__ eagg, float* __restrict__ h2,
                        int nE) {
    long long stride = (long long)gridDim.x * blockDim.x;
    for (long long gid = (long long)blockIdx.x * blockDim.x + threadIdx.x;
         gid < 16LL * nE; gid += stride) {
        int e = (int)(gid >> 4);
        int j = (int)(gid & 15);
        atomicAdd(&h2[dst[e] * 16 + j], eagg[src[e] * 16 + j]);
    }
}

// ============================= node kernels ================================

template <bool DEG_FROM_CSR>
__global__ __launch_bounds__(256) void k_nodeA(
    const float* __restrict__ x,
    const float* __restrict__ W_ego, const float* __restrict__ b_ego,
    const float* __restrict__ W_peer, const float* __restrict__ b_peer,
    const float* __restrict__ degf, const int* __restrict__ rowstart,
    const float* __restrict__ easum,
    const float* __restrict__ eagg, const float* __restrict__ h2,
    float* __restrict__ femb, int nN) {
    __shared__ float sWe[64 * 32];   // W_ego [k][32]
    __shared__ float sWp[64 * 48];   // W_peer rows 0..63 (x part)
    __shared__ float sWpe[96];       // W_peer rows 64,65 (edge-attr part)
    __shared__ float sbe[32];
    __shared__ float sbp[48];
    for (int i = threadIdx.x; i < 64 * 32; i += 256) sWe[i] = W_ego[i];
    for (int i = threadIdx.x; i < 64 * 48; i += 256) sWp[i] = W_peer[i];
    if (threadIdx.x < 96) sWpe[threadIdx.x] = W_peer[64 * 48 + threadIdx.x];
    if (threadIdx.x < 32) sbe[threadIdx.x] = b_ego[threadIdx.x];
    if (threadIdx.x < 48) sbp[threadIdx.x] = b_peer[threadIdx.x];
    __syncthreads();

    int v = blockIdx.x * 256 + threadIdx.x;
    if (v >= nN) return;

    float accE[32];
    float accP[48];
#pragma unroll
    for (int j = 0; j < 32; ++j) accE[j] = 0.f;
#pragma unroll
    for (int j = 0; j < 48; ++j) accP[j] = 0.f;

    const float4* x4 = (const float4*)(x + (long long)v * 64);
#pragma unroll 4
    for (int k4 = 0; k4 < 16; ++k4) {
        float4 xv = x4[k4];
        float xs[4] = {xv.x, xv.y, xv.z, xv.w};
#pragma unroll
        for (int t = 0; t < 4; ++t) {
            int k = 4 * k4 + t;
            float xk = xs[t];
            const float* we = &sWe[k * 32];
#pragma unroll
            for (int j = 0; j < 32; ++j) accE[j] = fmaf(xk, we[j], accE[j]);
            const float* wp = &sWp[k * 48];
#pragma unroll
            for (int j = 0; j < 48; ++j) accP[j] = fmaf(xk, wp[j], accP[j]);
        }
    }

    float dg;
    if (DEG_FROM_CSR) dg = (float)(rowstart[v + 1] - rowstart[v]);
    else              dg = degf[v];
    float dinv = dg > 0.f ? 1.0f / sqrtf(dg) : 0.f;
    float ea0 = easum[2 * v], ea1 = easum[2 * v + 1];

    float* fo = femb + (long long)v * 112;
#pragma unroll
    for (int j = 0; j < 32; ++j) fo[j] = fmaxf(accE[j] + sbe[j], 0.f);
#pragma unroll
    for (int j = 0; j < 16; ++j) fo[32 + j] = eagg[v * 16 + j];
#pragma unroll
    for (int j = 0; j < 16; ++j) fo[48 + j] = dinv * h2[v * 16 + j];
#pragma unroll
    for (int j = 0; j < 48; ++j) {
        float t = dg * (accP[j] + sbp[j]) + fmaf(ea0, sWpe[j], ea1 * sWpe[48 + j]);
        fo[64 + j] = fmaxf(dinv * t, 0.f);
    }
}

__global__ __launch_bounds__(256) void k_nodeB(
    const float* __restrict__ femb,
    const float* __restrict__ W_emb, const float* __restrict__ b_emb,
    const float* __restrict__ bn_g, const float* __restrict__ bn_b,
    const float* __restrict__ bn_m, const float* __restrict__ bn_v,
    const float* __restrict__ W0, const float* __restrict__ b0,
    const float* __restrict__ W1, const float* __restrict__ b1,
    float* __restrict__ out, int nN) {
    __shared__ float sW[112 * 64];   // W_emb [k][64]
    __shared__ float sbias[64], sScale[64], sShift[64], sW0[64], sW1[64];
    for (int i = threadIdx.x; i < 112 * 64; i += 256) sW[i] = W_emb[i];
    if (threadIdx.x < 64) {
        int j = threadIdx.x;
        sbias[j] = b_emb[j];
        float rstd = 1.0f / sqrtf(bn_v[j] + 1e-5f);
        float sc = bn_g[j] * rstd;
        sScale[j] = sc;
        sShift[j] = bn_b[j] - bn_m[j] * sc;
        sW0[j] = W0[j];
        sW1[j] = W1[j];
    }
    __syncthreads();

    int v = blockIdx.x * 256 + threadIdx.x;
    if (v >= nN) return;

    float acc[64];
#pragma unroll
    for (int j = 0; j < 64; ++j) acc[j] = 0.f;

    const float4* f4 = (const float4*)(femb + (long long)v * 112);
#pragma unroll 4
    for (int k4 = 0; k4 < 28; ++k4) {
        float4 fv = f4[k4];
        float fs[4] = {fv.x, fv.y, fv.z, fv.w};
#pragma unroll
        for (int t = 0; t < 4; ++t) {
            int k = 4 * k4 + t;
            float fk = fs[t];
            const float* wr = &sW[k * 64];
#pragma unroll
            for (int j = 0; j < 64; ++j) acc[j] = fmaf(fk, wr[j], acc[j]);
        }
    }

    float y0 = 0.f, y1 = 0.f;
#pragma unroll
    for (int j = 0; j < 64; ++j) {
        float e = fmaxf(acc[j] + sbias[j], 0.f);
        e = fmaf(e, sScale[j], sShift[j]);   // BN inference affine
        e = tanhf(e);
        acc[j] = e;
        y0 = fmaf(e, sW0[j], y0);
        y1 = fmaf(e, sW1[j], y1);
    }

    float4* o4 = (float4*)(out + 2LL * nN + (long long)v * 64);
#pragma unroll
    for (int j4 = 0; j4 < 16; ++j4)
        o4[j4] = make_float4(acc[4 * j4], acc[4 * j4 + 1], acc[4 * j4 + 2], acc[4 * j4 + 3]);
    out[v] = y0 + b0[0];
    out[nN + v] = y1 + b1[0];
}

// ================================ launch ===================================

extern "C" void kernel_launch(void* const* d_in, const int* in_sizes, int n_in,
                              void* d_out, int out_size, void* d_ws, size_t ws_size,
                              hipStream_t stream) {
    const float* x      = (const float*)d_in[0];
    const float* ea     = (const float*)d_in[1];
    const int*   src    = (const int*)d_in[3];
    const int*   dst    = (const int*)d_in[4];
    const float* W_peer = (const float*)d_in[5];
    const float* b_peer = (const float*)d_in[6];
    const float* W_ego  = (const float*)d_in[7];
    const float* b_ego  = (const float*)d_in[8];
    const float* W_edge = (const float*)d_in[9];
    const float* b_edge = (const float*)d_in[10];
    const float* W_emb  = (const float*)d_in[11];
    const float* b_emb  = (const float*)d_in[12];
    const float* bn_g   = (const float*)d_in[13];
    const float* bn_b   = (const float*)d_in[14];
    const float* bn_m   = (const float*)d_in[15];
    const float* bn_v   = (const float*)d_in[16];
    const float* W0     = (const float*)d_in[17];
    const float* b0     = (const float*)d_in[18];
    const float* W1     = (const float*)d_in[19];
    const float* b1     = (const float*)d_in[20];

    int nE = in_sizes[3];
    int nN = in_sizes[2];

    int nBlocks  = (nN + 255) / 256;          // node kernels
    int ngBlocks = (16 * nN + 255) / 256;     // 16-thread-per-node kernels
    int eBlocks1 = (nE + 255) / 256;          // 1-thread-per-edge kernels

    // element budgets (4B units)
    size_t preP     = (size_t)3 * nN + 4;                 // counts|rowstart|cursor
    size_t prePAl   = (preP + 3) & ~(size_t)3;            // 16B-align payload
    size_t packedEl = prePAl + 4ULL * nE + 146ULL * nN;   // packed tier
    size_t oldAEl   = (size_t)149 * nN + 4 + 2ULL * nE;   // csrc tier

    if (ws_size >= 4 * packedEl) {
        // ---------------- packed tier ----------------
        int*   wsi      = (int*)d_ws;
        int*   counts   = wsi;                        // N
        int*   rowstart = wsi + nN;                   // N+1 (pad to N+4)
        int*   cursor   = wsi + 2 * nN + 4;           // N
        int4*  payload  = (int4*)(wsi + prePAl);      // E x 16B
        float* eagg     = (float*)(wsi + prePAl + 4ULL * nE);  // 16N
        float* easum    = eagg + 16LL * nN;           // 2N
        float* h2       = easum + 2LL * nN;           // 16N
        float* femb     = h2 + 16LL * nN;             // 112N

        hipMemsetAsync(counts, 0, sizeof(int) * (size_t)nN, stream);
        k_count<<<eBlocks1, 256, 0, stream>>>(dst, counts, nE);
        k_scan<<<1, 1024, 0, stream>>>(counts, rowstart, cursor, nN, nE);
        k_fillP<<<eBlocks1, 256, 0, stream>>>(dst, src, ea, cursor, payload, nE);
        k_aggP1<<<ngBlocks, 256, 0, stream>>>(payload, rowstart, W_edge, b_edge,
                                              eagg, easum, nN);
        k_aggP2<<<ngBlocks, 256, 0, stream>>>(payload, rowstart, eagg, h2, nN);
        k_nodeA<true><<<nBlocks, 256, 0, stream>>>(x, W_ego, b_ego, W_peer, b_peer,
                                                   nullptr, rowstart, easum,
                                                   eagg, h2, femb, nN);
        k_nodeB<<<nBlocks, 256, 0, stream>>>(femb, W_emb, b_emb, bn_g, bn_b, bn_m,
                                             bn_v, W0, b0, W1, b1, (float*)d_out, nN);
    } else if (ws_size >= 4 * oldAEl) {
        // ---------------- csrc tier ----------------
        int*   wsi      = (int*)d_ws;
        int*   counts   = wsi;
        int*   rowstart = wsi + nN;
        int*   cursor   = wsi + 2 * nN + 4;
        int*   edgeid   = wsi + 3 * nN + 4;
        int*   csrc     = edgeid + nE;
        float* eagg     = (float*)(csrc + nE);
        float* easum    = eagg + 16LL * nN;
        float* h2       = easum + 2LL * nN;
        float* femb     = h2 + 16LL * nN;

        hipMemsetAsync(counts, 0, sizeof(int) * (size_t)nN, stream);
        k_count<<<eBlocks1, 256, 0, stream>>>(dst, counts, nE);
        k_scan<<<1, 1024, 0, stream>>>(counts, rowstart, cursor, nN, nE);
        k_fill<true><<<eBlocks1, 256, 0, stream>>>(dst, src, cursor, edgeid,
                                                   csrc, nE);
        k_agg1<<<ngBlocks, 256, 0, stream>>>(ea, edgeid, rowstart, W_edge, b_edge,
                                             eagg, easum, nN);
        k_agg2c<<<ngBlocks, 256, 0, stream>>>(csrc, rowstart, eagg, h2, nN);
        k_nodeA<true><<<nBlocks, 256, 0, stream>>>(x, W_ego, b_ego, W_peer, b_peer,
                                                   nullptr, rowstart, easum,
                                                   eagg, h2, femb, nN);
        k_nodeB<<<nBlocks, 256, 0, stream>>>(femb, W_emb, b_emb, bn_g, bn_b, bn_m,
                                             bn_v, W0, b0, W1, b1, (float*)d_out, nN);
    } else {
        // ---------------- atomic tier ----------------
        float* wsf   = (float*)d_ws;
        float* deg   = wsf;                  // N
        float* easum = wsf + nN;             // 2N
        float* eagg  = wsf + 3LL * nN;       // 16N
        float* h2    = wsf + 19LL * nN;      // 16N
        float* femb  = wsf + 35LL * nN;      // 112N

        hipMemsetAsync(wsf, 0, sizeof(float) * 35ULL * nN, stream);
        const int eBlocks = 2048;
        k_edge1<<<eBlocks, 256, 0, stream>>>(ea, dst, W_edge, b_edge, deg, easum,
                                             eagg, nE);
        k_edge2<<<eBlocks, 256, 0, stream>>>(src, dst, eagg, h2, nE);
        k_nodeA<false><<<nBlocks, 256, 0, stream>>>(x, W_ego, b_ego, W_peer, b_peer,
                                                    deg, nullptr, easum,
                                                    eagg, h2, femb, nN);
        k_nodeB<<<nBlocks, 256, 0, stream>>>(femb, W_emb, b_emb, bn_g, bn_b, bn_m,
                                             bn_v, W0, b0, W1, b1, (float*)d_out, nN);
    }
}